// Round 5
// baseline (328.040 us; speedup 1.0000x reference)
//
#include <hip/hip_runtime.h>

// GNN_41051297415239: 2-layer GraphSAGE + linear skip on MI355X (gfx950)
// N=100000 nodes, E=1600000 edges, F_IN=64, HID=128, OUT=64
//
// R15 -> R16 (direct-bucket CSR; hex-volley reverted to oct):
//   All 5 dispatches measured ~40us each (everything below the fill
//   floor; total 225 = ~5x40 + gaps). The dst-sorted CSR (bscatter
//   2-pass LDS hist + csr_build hist/scan/scatter + 7.2MB ebuf round
//   trip) buys nothing over a DIRECT padded bucket build: one pass,
//   r = atomicAdd(&cnt[d],1); csrD[d*64+r] = src.  (cap 64 = +12 sigma
//   over mean deg 16 -- same assumption class as old CAP2/+16sigma.)
//   Eliminates csr_build dispatch + ebuf entirely; edge path becomes
//   3125 uniform 1-edge/thread blocks. aggs read cnt[] instead of rpack.
//
// Algebra:
//   h   = relu( [mean1 | x] @ [W1n ; W1r+Wl1] + (b1n+bl1) )   (K=128 GEMM)
//   p   = h @ W2n        (project BEFORE aggregating: 64-wide gather)
//   out = mean(p) + h @ (W2r+Wl2) + (b2n+bl2)

#define NN 100000
#define NE 1600000
#define CAPD 64         // padded per-dst capacity (mean 16, +12 sigma)
#define MB 256          // rows per gemmF block
#define EB 3125         // edge-scatter blocks (NE / 512 exactly)
#define W1B 32          // W1 build blocks (32 x 512 = 16384 elems)
#define W2B 32          // W2 build blocks
#define XBLK ((NN * 8 + 511) / 512)   // 1563 x-conversion blocks

typedef __attribute__((ext_vector_type(8))) __bf16 bf16x8;
typedef __attribute__((ext_vector_type(4))) float f32x4;

__device__ __forceinline__ float b2f(unsigned short u) {
    unsigned v = ((unsigned)u) << 16;
    float f;
    __builtin_memcpy(&f, &v, 4);
    return f;
}
__device__ __forceinline__ float b2f_lo(unsigned v) {
    unsigned w = v << 16;
    float f;
    __builtin_memcpy(&f, &w, 4);
    return f;
}
__device__ __forceinline__ float b2f_hi(unsigned v) {
    unsigned w = v & 0xFFFF0000u;
    float f;
    __builtin_memcpy(&f, &w, 4);
    return f;
}
__device__ __forceinline__ unsigned short f2b(float f) {
    unsigned u;
    __builtin_memcpy(&u, &f, 4);
    u += 0x7FFFu + ((u >> 16) & 1u);   // round-to-nearest-even
    return (unsigned short)(u >> 16);
}

// Fused front kernel: per-block inline dtype sniffing.
//   blocks [0, EB):             edge scatter -> cnt/csrD (direct bucket)
//   blocks [EB, EB+W1B):        build Wt1g (+bias1, +flags on first block)
//   blocks [.., EB+W1B+W2B):    build Wt2g (+bias2)
//   blocks [.., ..+XBLK):       canonicalize x -> bf16
__global__ __launch_bounds__(512) void front_kernel(
    const void* __restrict__ x, const int* __restrict__ ei,
    const void* W1n, const void* W1r, const void* Wl1,
    const void* b1n, const void* bl1,
    const void* W2n, const void* W2r, const void* Wl2,
    const void* b2n, const void* bl2,
    unsigned short* __restrict__ Wt1g, unsigned short* __restrict__ Wt2g,
    float* __restrict__ bias1, float* __restrict__ bias2,
    unsigned int* __restrict__ xbu,
    int* __restrict__ flags, int* __restrict__ cnt, int* __restrict__ csrD) {
    __shared__ int sred[256];   // inline sniff reduction
    int t = threadIdx.x;
    int b = blockIdx.x;

    if (b < EB) {
        // --- edge path: inline i64 sniff (all-zero high words) ---
        if (t < 256) sred[t] = ei[2 * t + 1];
        __syncthreads();
        for (int s = 128; s > 0; s >>= 1) {
            if (t < s) sred[t] |= sred[t + s];
            __syncthreads();
        }
        bool i64 = (sred[0] == 0);
        int e = b * 512 + t;            // EB*512 == NE exactly
        int s, d;
        if (i64) { const long long* q = (const long long*)ei; s = (int)q[e]; d = (int)q[NE + e]; }
        else     { s = ei[e]; d = ei[NE + e]; }
        int r = atomicAdd(&cnt[d], 1);
        if (r < CAPD) csrD[(size_t)d * CAPD + r] = s;
        return;
    }

    // --- prep paths: inline fp32 sniff (exponent-field vote on x) ---
    const unsigned int* xw = (const unsigned int*)x;
    if (t < 256) {
        unsigned e = (xw[t] >> 7) & 0xFFu;
        sred[t] = (e > 0x85u) ? 1 : 0;
    }
    __syncthreads();
    for (int s = 128; s > 0; s >>= 1) {
        if (t < s) sred[t] += sred[t + s];
        __syncthreads();
    }
    bool fp32 = sred[0] >= 32;
    auto rd = [&](const void* p, int i) -> float {
        return fp32 ? ((const float*)p)[i] : b2f(((const unsigned short*)p)[i]);
    };

    if (b < EB + W1B) {
        // W1 build: consecutive tid -> consecutive k -> coalesced 2B writes.
        int idx = (b - EB) * 512 + t;
        int c = idx >> 7, k = idx & 127;
        float v = (k < 64) ? rd(W1n, k * 128 + c)
                           : rd(W1r, (k - 64) * 128 + c) + rd(Wl1, (k - 64) * 128 + c);
        Wt1g[c * 128 + k] = f2b(v);
        if (b == EB) {
            if (t < 128) bias1[t] = rd(b1n, t) + rd(bl1, t);
            if (t == 0) flags[1] = fp32 ? 1 : 0;   // consumed by agg2
        }
        return;
    }
    if (b < EB + W1B + W2B) {
        int idx = (b - EB - W1B) * 512 + t;
        int c = idx >> 7, k = idx & 127;
        float v = (c < 64) ? rd(W2n, k * 64 + c)
                           : rd(W2r, k * 64 + (c - 64)) + rd(Wl2, k * 64 + (c - 64));
        Wt2g[c * 128 + k] = f2b(v);
        if (b == EB + W1B && t < 64) bias2[t] = rd(b2n, t) + rd(bl2, t);
        return;
    }
    // x canonicalization: one uint4 (8 bf16 / 8 fp32->bf16) per thread.
    int tt = (b - EB - W1B - W2B) * 512 + t;
    if (tt >= NN * 8) return;
    if (fp32) {
        const float4* xf = (const float4*)x;
        float4 a = xf[2 * tt], c = xf[2 * tt + 1];
        uint4 o;
        o.x = f2b(a.x) | ((unsigned)f2b(a.y) << 16);
        o.y = f2b(a.z) | ((unsigned)f2b(a.w) << 16);
        o.z = f2b(c.x) | ((unsigned)f2b(c.y) << 16);
        o.w = f2b(c.z) | ((unsigned)f2b(c.w) << 16);
        ((uint4*)xbu)[tt] = o;
    } else {
        ((uint4*)xbu)[tt] = ((const uint4*)x)[tt];
    }
}

// --- Slot-per-dst gather: wave = 8 dsts, 8 lanes/dst, 16B row-loads ---
// Oct loop with UNCONDITIONAL loads: 8 rows in flight per slot.

__device__ __forceinline__ void gather_acc(
    const unsigned short* __restrict__ feat, const int* __restrict__ csr,
    int base, int deg, int fo, float* acc) {
    int t = 0;
    for (; t + 8 <= deg; t += 8) {
        int i0 = csr[base + t],     i1 = csr[base + t + 1];
        int i2 = csr[base + t + 2], i3 = csr[base + t + 3];
        int i4 = csr[base + t + 4], i5 = csr[base + t + 5];
        int i6 = csr[base + t + 6], i7 = csr[base + t + 7];
        bf16x8 v0 = *(const bf16x8*)(feat + (size_t)i0 * 64 + fo);
        bf16x8 v1 = *(const bf16x8*)(feat + (size_t)i1 * 64 + fo);
        bf16x8 v2 = *(const bf16x8*)(feat + (size_t)i2 * 64 + fo);
        bf16x8 v3 = *(const bf16x8*)(feat + (size_t)i3 * 64 + fo);
        bf16x8 v4 = *(const bf16x8*)(feat + (size_t)i4 * 64 + fo);
        bf16x8 v5 = *(const bf16x8*)(feat + (size_t)i5 * 64 + fo);
        bf16x8 v6 = *(const bf16x8*)(feat + (size_t)i6 * 64 + fo);
        bf16x8 v7 = *(const bf16x8*)(feat + (size_t)i7 * 64 + fo);
#pragma unroll
        for (int k = 0; k < 8; ++k)
            acc[k] += (((float)v0[k] + (float)v1[k]) + ((float)v2[k] + (float)v3[k]))
                    + (((float)v4[k] + (float)v5[k]) + ((float)v6[k] + (float)v7[k]));
    }
    for (; t + 4 <= deg; t += 4) {
        int i0 = csr[base + t],     i1 = csr[base + t + 1];
        int i2 = csr[base + t + 2], i3 = csr[base + t + 3];
        bf16x8 v0 = *(const bf16x8*)(feat + (size_t)i0 * 64 + fo);
        bf16x8 v1 = *(const bf16x8*)(feat + (size_t)i1 * 64 + fo);
        bf16x8 v2 = *(const bf16x8*)(feat + (size_t)i2 * 64 + fo);
        bf16x8 v3 = *(const bf16x8*)(feat + (size_t)i3 * 64 + fo);
#pragma unroll
        for (int k = 0; k < 8; ++k)
            acc[k] += ((float)v0[k] + (float)v1[k]) + ((float)v2[k] + (float)v3[k]);
    }
    for (; t < deg; ++t) {
        int i = csr[base + t];
        bf16x8 v = *(const bf16x8*)(feat + (size_t)i * 64 + fo);
#pragma unroll
        for (int k = 0; k < 8; ++k) acc[k] += (float)v[k];
    }
}

// Layer-1 aggregation: write bf16 mean1[N,64].
__global__ __launch_bounds__(256) void agg1_kernel(
    const unsigned short* __restrict__ feat, const int* __restrict__ cnt,
    const int* __restrict__ csrD, unsigned int* __restrict__ mean1u) {
    int wid = threadIdx.x >> 6, lane = threadIdx.x & 63;
    int slot = lane >> 3, fo = (lane & 7) * 8;
    int d = (blockIdx.x * 4 + wid) * 8 + slot;
    int dd = min(d, NN - 1);
    int deg = min(cnt[dd], CAPD);
    int base = dd * CAPD;
    float acc[8];
#pragma unroll
    for (int k = 0; k < 8; ++k) acc[k] = 0.f;
    gather_acc(feat, csrD, base, deg, fo, acc);
    if (d < NN) {
        float r = 1.0f / fmaxf((float)deg, 1.0f);
        uint4 o;
        o.x = f2b(acc[0] * r) | ((unsigned)f2b(acc[1] * r) << 16);
        o.y = f2b(acc[2] * r) | ((unsigned)f2b(acc[3] * r) << 16);
        o.z = f2b(acc[4] * r) | ((unsigned)f2b(acc[5] * r) << 16);
        o.w = f2b(acc[6] * r) | ((unsigned)f2b(acc[7] * r) << 16);
        *(uint4*)(mean1u + (size_t)d * 32 + (lane & 7) * 4) = o;
    }
}

// Layer-2 aggregation fused with final epilogue:
// out = mean(p) + sf + bias2  (store fp32 or bf16 per flags[1]).
__global__ __launch_bounds__(256) void agg2_kernel(
    const unsigned short* __restrict__ p, const int* __restrict__ cnt,
    const int* __restrict__ csrD, const unsigned int* __restrict__ sfu,
    const float* __restrict__ bias2, const int* __restrict__ flags,
    void* __restrict__ out) {
    int wid = threadIdx.x >> 6, lane = threadIdx.x & 63;
    int slot = lane >> 3, fo = (lane & 7) * 8;
    int d = (blockIdx.x * 4 + wid) * 8 + slot;
    int dd = min(d, NN - 1);
    int deg = min(cnt[dd], CAPD);
    int base = dd * CAPD;
    float acc[8];
#pragma unroll
    for (int k = 0; k < 8; ++k) acc[k] = 0.f;
    gather_acc(p, csrD, base, deg, fo, acc);
    if (d < NN) {
        float r = 1.0f / fmaxf((float)deg, 1.0f);
        uint4 sv = *(const uint4*)(sfu + (size_t)d * 32 + (lane & 7) * 4);
        float4 bA = *(const float4*)(bias2 + fo);
        float4 bB = *(const float4*)(bias2 + fo + 4);
        float v0 = acc[0] * r + b2f_lo(sv.x) + bA.x;
        float v1 = acc[1] * r + b2f_hi(sv.x) + bA.y;
        float v2 = acc[2] * r + b2f_lo(sv.y) + bA.z;
        float v3 = acc[3] * r + b2f_hi(sv.y) + bA.w;
        float v4 = acc[4] * r + b2f_lo(sv.z) + bB.x;
        float v5 = acc[5] * r + b2f_hi(sv.z) + bB.y;
        float v6 = acc[6] * r + b2f_lo(sv.w) + bB.z;
        float v7 = acc[7] * r + b2f_hi(sv.w) + bB.w;
        if (flags[1]) {
            float* op = (float*)out + (size_t)d * 64 + fo;
            *(float4*)op = make_float4(v0, v1, v2, v3);
            *(float4*)(op + 4) = make_float4(v4, v5, v6, v7);
        } else {
            uint4 o;
            o.x = f2b(v0) | ((unsigned)f2b(v1) << 16);
            o.y = f2b(v2) | ((unsigned)f2b(v3) << 16);
            o.z = f2b(v4) | ((unsigned)f2b(v5) << 16);
            o.w = f2b(v6) | ((unsigned)f2b(v7) << 16);
            *(uint4*)((unsigned int*)out + (size_t)d * 32 + (lane & 7) * 4) = o;
        }
    }
}

// Fused GEMM v2: 512 thr / 8 waves / 256 rows per block (wave = 2 m-tiles).
// Phase 1: h = relu([mean1|xb]@W1t + b1), W1 in LDS, A prefetched to regs.
// h -> per-wave LDS tile (no barrier).
// Phase 2: p = h@W2n, sf = h@(W2r+Wl2), W2 ALSO in LDS, B-fragments
// prefetched 8-wide per k-step.
__global__ __launch_bounds__(512, 2) void gemmF_kernel(
    const unsigned short* __restrict__ mean1,
    const unsigned short* __restrict__ xb,
    const unsigned short* __restrict__ Wt1g, const float* __restrict__ bias1,
    const unsigned short* __restrict__ Wt2g,
    unsigned short* __restrict__ p, unsigned short* __restrict__ sf) {
    __shared__ unsigned short Wt1s[128 * 136];   // 34,816 B
    __shared__ unsigned short Wt2s[128 * 136];   // 34,816 B
    __shared__ unsigned short hs[MB * 136];      // 69,632 B  (total 139,264 B)
    int tid = threadIdx.x;
    int wid = tid >> 6, lane = tid & 63;
    int m = lane & 15, g = lane >> 4;
    int row0 = blockIdx.x * MB + wid * 32;

    // prefetch A fragments for both m-tiles (hidden behind weight staging)
    bf16x8 a_frag[2][4];
#pragma unroll
    for (int t = 0; t < 2; ++t) {
        int arow = min(row0 + t * 16 + m, NN - 1);
#pragma unroll
        for (int kt = 0; kt < 4; ++kt) {
            int k0 = kt * 32 + g * 8;
            a_frag[t][kt] = (k0 < 64)
                ? *(const bf16x8*)(mean1 + (size_t)arow * 64 + k0)
                : *(const bf16x8*)(xb + (size_t)arow * 64 + (k0 - 64));
        }
    }

    // stage BOTH weight matrices into LDS (8 x 16B per thread)
    for (int idx = tid; idx < 4096; idx += 512) {
        int c = (idx >> 4) & 127, ch = idx & 15;
        if (idx < 2048)
            *(bf16x8*)&Wt1s[c * 136 + ch * 8] = *(const bf16x8*)&Wt1g[c * 128 + ch * 8];
        else
            *(bf16x8*)&Wt2s[c * 136 + ch * 8] = *(const bf16x8*)&Wt2g[c * 128 + ch * 8];
    }
    __syncthreads();

    f32x4 acc[2][8];
#pragma unroll
    for (int t = 0; t < 2; ++t)
#pragma unroll
        for (int nt = 0; nt < 8; ++nt) acc[t][nt] = (f32x4){0.f, 0.f, 0.f, 0.f};

#pragma unroll
    for (int kt = 0; kt < 4; ++kt) {
        int k0 = kt * 32 + g * 8;
        bf16x8 b[8];
#pragma unroll
        for (int nt = 0; nt < 8; ++nt)
            b[nt] = *(const bf16x8*)(&Wt1s[(nt * 16 + m) * 136 + k0]);
#pragma unroll
        for (int nt = 0; nt < 8; ++nt) {
            acc[0][nt] = __builtin_amdgcn_mfma_f32_16x16x32_bf16(a_frag[0][kt], b[nt], acc[0][nt], 0, 0, 0);
            acc[1][nt] = __builtin_amdgcn_mfma_f32_16x16x32_bf16(a_frag[1][kt], b[nt], acc[1][nt], 0, 0, 0);
        }
    }

    // phase-1 epilogue: relu+bias -> hs (wave's own 32-row slice)
#pragma unroll
    for (int t = 0; t < 2; ++t)
#pragma unroll
        for (int nt = 0; nt < 8; ++nt) {
            int col = nt * 16 + m;
            float bias = bias1[col];
#pragma unroll
            for (int r = 0; r < 4; ++r) {
                float v = fmaxf(acc[t][nt][r] + bias, 0.0f);
                hs[(wid * 32 + t * 16 + g * 4 + r) * 136 + col] = f2b(v);
            }
        }
    // no __syncthreads: each wave reads only rows it wrote itself.

    bf16x8 a2[2][4];
#pragma unroll
    for (int t = 0; t < 2; ++t)
#pragma unroll
        for (int kt = 0; kt < 4; ++kt)
            a2[t][kt] = *(const bf16x8*)(&hs[(wid * 32 + t * 16 + m) * 136 + kt * 32 + g * 8]);

#pragma unroll
    for (int t = 0; t < 2; ++t)
#pragma unroll
        for (int nt = 0; nt < 8; ++nt) acc[t][nt] = (f32x4){0.f, 0.f, 0.f, 0.f};

#pragma unroll
    for (int kt = 0; kt < 4; ++kt) {
        int k0 = kt * 32 + g * 8;
        bf16x8 b[8];
#pragma unroll
        for (int nt = 0; nt < 8; ++nt)
            b[nt] = *(const bf16x8*)(&Wt2s[(nt * 16 + m) * 136 + k0]);
#pragma unroll
        for (int nt = 0; nt < 8; ++nt) {
            acc[0][nt] = __builtin_amdgcn_mfma_f32_16x16x32_bf16(a2[0][kt], b[nt], acc[0][nt], 0, 0, 0);
            acc[1][nt] = __builtin_amdgcn_mfma_f32_16x16x32_bf16(a2[1][kt], b[nt], acc[1][nt], 0, 0, 0);
        }
    }

#pragma unroll
    for (int t = 0; t < 2; ++t)
#pragma unroll
        for (int nt = 0; nt < 8; ++nt) {
            int col = nt * 16 + m;
#pragma unroll
            for (int r = 0; r < 4; ++r) {
                int row2 = row0 + t * 16 + g * 4 + r;
                if (row2 < NN) {
                    float v = acc[t][nt][r];
                    if (col < 64) p[(size_t)row2 * 64 + col] = f2b(v);
                    else          sf[(size_t)row2 * 64 + (col - 64)] = f2b(v);
                }
            }
        }
}

extern "C" void kernel_launch(void* const* d_in, const int* in_sizes, int n_in,
                              void* d_out, int out_size, void* d_ws, size_t ws_size,
                              hipStream_t stream) {
    const void* x   = d_in[0];
    const int*  ei  = (const int*)d_in[1];
    const void* W1n = d_in[2];
    const void* b1n = d_in[3];
    const void* W1r = d_in[4];
    const void* Wl1 = d_in[5];
    const void* bl1 = d_in[6];
    const void* W2n = d_in[7];
    const void* b2n = d_in[8];
    const void* W2r = d_in[9];
    const void* Wl2 = d_in[10];
    const void* bl2 = d_in[11];

    char* ws = (char*)d_ws;
    // total ~64.5 MB; p aliases xb (block-local producer/consumer in gemmF)
    int*            flags = (int*)(ws + 0);                    //      64 B
    int*            cnt   = (int*)(ws + 1024);                 // 400,000 B
    float*          bias1 = (float*)(ws + 402432);             //     512 B
    float*          bias2 = (float*)(ws + 402944);             //     256 B
    unsigned short* Wt1g  = (unsigned short*)(ws + 403200);    //  32,768 B
    unsigned short* Wt2g  = (unsigned short*)(ws + 435968);    //  32,768 B
    int*            csrD  = (int*)(ws + 468736);               // 25,600,000 B (NN*CAPD*4)
    unsigned short* xb    = (unsigned short*)(ws + 26068736);  // 12,800,000 B
    unsigned short* p     = xb;                                // (row-local alias)
    unsigned short* mean1 = (unsigned short*)(ws + 38868736);  // 12,800,000 B
    unsigned short* sf    = (unsigned short*)(ws + 51668736);  // 12,800,000 B

    (void)in_sizes; (void)n_in; (void)out_size; (void)ws_size;

    // zero per-dst degree counters (poisoned workspace)
    hipMemsetAsync(cnt, 0, NN * sizeof(int), stream);
    // fused front: edge scatter (direct bucket) + weight build + x convert
    front_kernel<<<EB + W1B + W2B + XBLK, 512, 0, stream>>>(
        x, ei, W1n, W1r, Wl1, b1n, bl1, W2n, W2r, Wl2, b2n, bl2,
        Wt1g, Wt2g, bias1, bias2, (unsigned int*)xb, flags, cnt, csrD);
    // layer 1 aggregation (32 dsts per block: 4 waves x 8 slots)
    agg1_kernel<<<(NN + 31) / 32, 256, 0, stream>>>(xb, cnt, csrD, (unsigned int*)mean1);
    // fused GEMM v2 (256 rows/block, both weights in LDS)
    gemmF_kernel<<<(NN + MB - 1) / MB, 512, 0, stream>>>(mean1, xb, Wt1g, bias1, Wt2g, p, sf);
    // layer 2 aggregation + epilogue
    agg2_kernel<<<(NN + 31) / 32, 256, 0, stream>>>(p, cnt, csrD, (const unsigned int*)sf,
                                                    bias2, flags, d_out);
}

// Round 6
// 220.871 us; speedup vs baseline: 1.4852x; 1.4852x over previous
//
#include <hip/hip_runtime.h>

// GNN_41051297415239: 2-layer GraphSAGE + linear skip on MI355X (gfx950)
// N=100000 nodes, E=1600000 edges, F_IN=64, HID=128, OUT=64
//
// R16 -> R17: REVERT direct-bucket (R16: front=163us, occupancy 75%,
//   VALUBusy 1.2% -- random returning atomics + 4B scatter = latency
//   chain). Back to R14 structure (223us proven), with ONE change:
//   finer super-buckets. SB width 1024 -> 256 dsts (NSB 98 -> 391,
//   CAP2 18432 -> 5120 = mean 4096 + 16 sigma). csr_build was the worst
//   kernel per byte (~38us for 13MB, 98 blocks = 38% CU coverage,
//   20-barrier scan): now 391 blocks, 256-counter hist, 8-step scan.
//   bscatter: only shift/mask change. aggs/gemmF/front: exact R14.
//
// Algebra:
//   h   = relu( [mean1 | x] @ [W1n ; W1r+Wl1] + (b1n+bl1) )   (K=128 GEMM)
//   p   = h @ W2n        (project BEFORE aggregating: 64-wide gather)
//   out = mean(p) + h @ (W2r+Wl2) + (b2n+bl2)

#define NN 100000
#define NE 1600000
#define SBW 256         // dsts per super-bucket
#define NSB 391         // ceil(NN/SBW)
#define CAP2 5120       // padded SB capacity (mean 4096, +16 sigma)
#define EPB 6250        // edges per bscatter block (256 blocks)
#define MB 256          // rows per gemmF block
#define BSB 256         // bscatter blocks in fused front kernel
#define W1B 32          // W1 build blocks (32 x 512 = 16384 elems)
#define W2B 32          // W2 build blocks
#define XBLK ((NN * 8 + 511) / 512)   // 1563 x-conversion blocks

typedef __attribute__((ext_vector_type(8))) __bf16 bf16x8;
typedef __attribute__((ext_vector_type(4))) float f32x4;

__device__ __forceinline__ float b2f(unsigned short u) {
    unsigned v = ((unsigned)u) << 16;
    float f;
    __builtin_memcpy(&f, &v, 4);
    return f;
}
__device__ __forceinline__ float b2f_lo(unsigned v) {
    unsigned w = v << 16;
    float f;
    __builtin_memcpy(&f, &w, 4);
    return f;
}
__device__ __forceinline__ float b2f_hi(unsigned v) {
    unsigned w = v & 0xFFFF0000u;
    float f;
    __builtin_memcpy(&f, &w, 4);
    return f;
}
__device__ __forceinline__ unsigned short f2b(float f) {
    unsigned u;
    __builtin_memcpy(&u, &f, 4);
    u += 0x7FFFu + ((u >> 16) & 1u);   // round-to-nearest-even
    return (unsigned short)(u >> 16);
}

// Fused front kernel: per-block inline dtype sniffing.
//   blocks [0, BSB):            bscatter (dst cached in LDS between passes)
//   blocks [BSB, BSB+W1B):      build Wt1g (+bias1, +flags on first block)
//   blocks [.., BSB+W1B+W2B):   build Wt2g (+bias2)
//   blocks [.., ..+XBLK):       canonicalize x -> bf16
__global__ __launch_bounds__(512) void front_kernel(
    const void* __restrict__ x, const int* __restrict__ ei,
    const void* W1n, const void* W1r, const void* Wl1,
    const void* b1n, const void* bl1,
    const void* W2n, const void* W2r, const void* Wl2,
    const void* b2n, const void* bl2,
    unsigned short* __restrict__ Wt1g, unsigned short* __restrict__ Wt2g,
    float* __restrict__ bias1, float* __restrict__ bias2,
    unsigned int* __restrict__ xbu,
    int* __restrict__ flags, int* __restrict__ cntP, int* __restrict__ ebuf) {
    __shared__ int lh[NSB];     // bscatter: counts, then rank cursor
    __shared__ int lbase[NSB];  // bscatter: block's reserved base per SB
    __shared__ int ldst[EPB];   // bscatter: cached dst indices
    __shared__ int sred[256];   // inline sniff reduction
    int t = threadIdx.x;
    int b = blockIdx.x;

    if (b < BSB) {
        // --- bscatter path: inline i64 sniff (all-zero high words) ---
        if (t < 256) sred[t] = ei[2 * t + 1];
        if (t < NSB) lh[t] = 0;
        __syncthreads();
        for (int s = 128; s > 0; s >>= 1) {
            if (t < s) sred[t] |= sred[t + s];
            __syncthreads();
        }
        bool i64 = (sred[0] == 0);
        int e0 = b * EPB;
        for (int i = t; i < EPB; i += 512) {
            int e = e0 + i;
            int d = i64 ? (int)((const long long*)ei)[NE + e] : ei[NE + e];
            ldst[i] = d;
            atomicAdd(&lh[d >> 8], 1);
        }
        __syncthreads();
        if (t < NSB) {
            int c = lh[t];
            lbase[t] = c ? atomicAdd(&cntP[t * 16], c) : 0;
            lh[t] = 0;
        }
        __syncthreads();
        for (int i = t; i < EPB; i += 512) {
            int e = e0 + i;
            int s = i64 ? (int)((const long long*)ei)[e] : ei[e];
            int d = ldst[i];
            int sb = d >> 8;
            int r = lbase[sb] + atomicAdd(&lh[sb], 1);
            if (r < CAP2) ebuf[sb * CAP2 + r] = (s << 8) | (d & 255);
        }
        return;
    }

    // --- prep paths: inline fp32 sniff (exponent-field vote on x) ---
    const unsigned int* xw = (const unsigned int*)x;
    if (t < 256) {
        unsigned e = (xw[t] >> 7) & 0xFFu;
        sred[t] = (e > 0x85u) ? 1 : 0;
    }
    __syncthreads();
    for (int s = 128; s > 0; s >>= 1) {
        if (t < s) sred[t] += sred[t + s];
        __syncthreads();
    }
    bool fp32 = sred[0] >= 32;
    auto rd = [&](const void* p, int i) -> float {
        return fp32 ? ((const float*)p)[i] : b2f(((const unsigned short*)p)[i]);
    };

    if (b < BSB + W1B) {
        // W1 build: consecutive tid -> consecutive k -> coalesced 2B writes.
        int idx = (b - BSB) * 512 + t;
        int c = idx >> 7, k = idx & 127;
        float v = (k < 64) ? rd(W1n, k * 128 + c)
                           : rd(W1r, (k - 64) * 128 + c) + rd(Wl1, (k - 64) * 128 + c);
        Wt1g[c * 128 + k] = f2b(v);
        if (b == BSB) {
            if (t < 128) bias1[t] = rd(b1n, t) + rd(bl1, t);
            if (t == 0) flags[1] = fp32 ? 1 : 0;   // consumed by agg2
        }
        return;
    }
    if (b < BSB + W1B + W2B) {
        int idx = (b - BSB - W1B) * 512 + t;
        int c = idx >> 7, k = idx & 127;
        float v = (c < 64) ? rd(W2n, k * 64 + c)
                           : rd(W2r, k * 64 + (c - 64)) + rd(Wl2, k * 64 + (c - 64));
        Wt2g[c * 128 + k] = f2b(v);
        if (b == BSB + W1B && t < 64) bias2[t] = rd(b2n, t) + rd(bl2, t);
        return;
    }
    // x canonicalization: one uint4 (8 bf16 / 8 fp32->bf16) per thread.
    int tt = (b - BSB - W1B - W2B) * 512 + t;
    if (tt >= NN * 8) return;
    if (fp32) {
        const float4* xf = (const float4*)x;
        float4 a = xf[2 * tt], c = xf[2 * tt + 1];
        uint4 o;
        o.x = f2b(a.x) | ((unsigned)f2b(a.y) << 16);
        o.y = f2b(a.z) | ((unsigned)f2b(a.w) << 16);
        o.z = f2b(c.x) | ((unsigned)f2b(c.y) << 16);
        o.w = f2b(c.z) | ((unsigned)f2b(c.w) << 16);
        ((uint4*)xbu)[tt] = o;
    } else {
        ((uint4*)xbu)[tt] = ((const uint4*)x)[tt];
    }
}

// One block (512 thr) per super-bucket (256 dsts): 256-counter LDS hist +
// 8-step scan -> rpack[d] = (abs_start<<8)|deg, dst-sorted csr into the
// SB's dense window.
__global__ __launch_bounds__(512) void csr_build_kernel(
    const int* __restrict__ ebuf, const int* __restrict__ cntP,
    int* __restrict__ rpack, int* __restrict__ csr) {
    __shared__ int lcnt[SBW];
    __shared__ int lcur[SBW];
    int t = threadIdx.x, b = blockIdx.x;
    if (t < SBW) lcnt[t] = 0;
    __syncthreads();
    int base = b * CAP2;
    int cnt = min(cntP[b * 16], CAP2);
    for (int i = t; i < cnt; i += 512) atomicAdd(&lcnt[ebuf[base + i] & 255], 1);
    __syncthreads();
    int c = (t < SBW) ? lcnt[t] : 0;
    if (t < SBW) lcur[t] = c;
    __syncthreads();
    for (int off = 1; off < SBW; off <<= 1) {   // Hillis-Steele inclusive
        int add = 0;
        if (t < SBW && t >= off) add = lcur[t - off];
        __syncthreads();
        if (t < SBW) lcur[t] += add;
        __syncthreads();
    }
    if (t < SBW) {
        int excl = lcur[t] - c;                 // exclusive prefix
        int d0 = b * SBW + t;
        if (d0 < NN) rpack[d0] = ((base + excl) << 8) | min(c, 255);
        lcur[t] = excl;                         // becomes scatter cursor
    }
    __syncthreads();
    for (int i = t; i < cnt; i += 512) {
        int pk = ebuf[base + i];
        int r = atomicAdd(&lcur[pk & 255], 1);
        csr[base + r] = pk >> 8;
    }
}

// --- Slot-per-dst gather: wave = 8 dsts, 8 lanes/dst, 16B row-loads ---
// Oct loop with UNCONDITIONAL loads: 8 rows in flight per slot.

__device__ __forceinline__ void gather_acc(
    const unsigned short* __restrict__ feat, const int* __restrict__ csr,
    int base, int deg, int fo, float* acc) {
    int t = 0;
    for (; t + 8 <= deg; t += 8) {
        int i0 = csr[base + t],     i1 = csr[base + t + 1];
        int i2 = csr[base + t + 2], i3 = csr[base + t + 3];
        int i4 = csr[base + t + 4], i5 = csr[base + t + 5];
        int i6 = csr[base + t + 6], i7 = csr[base + t + 7];
        bf16x8 v0 = *(const bf16x8*)(feat + (size_t)i0 * 64 + fo);
        bf16x8 v1 = *(const bf16x8*)(feat + (size_t)i1 * 64 + fo);
        bf16x8 v2 = *(const bf16x8*)(feat + (size_t)i2 * 64 + fo);
        bf16x8 v3 = *(const bf16x8*)(feat + (size_t)i3 * 64 + fo);
        bf16x8 v4 = *(const bf16x8*)(feat + (size_t)i4 * 64 + fo);
        bf16x8 v5 = *(const bf16x8*)(feat + (size_t)i5 * 64 + fo);
        bf16x8 v6 = *(const bf16x8*)(feat + (size_t)i6 * 64 + fo);
        bf16x8 v7 = *(const bf16x8*)(feat + (size_t)i7 * 64 + fo);
#pragma unroll
        for (int k = 0; k < 8; ++k)
            acc[k] += (((float)v0[k] + (float)v1[k]) + ((float)v2[k] + (float)v3[k]))
                    + (((float)v4[k] + (float)v5[k]) + ((float)v6[k] + (float)v7[k]));
    }
    for (; t + 4 <= deg; t += 4) {
        int i0 = csr[base + t],     i1 = csr[base + t + 1];
        int i2 = csr[base + t + 2], i3 = csr[base + t + 3];
        bf16x8 v0 = *(const bf16x8*)(feat + (size_t)i0 * 64 + fo);
        bf16x8 v1 = *(const bf16x8*)(feat + (size_t)i1 * 64 + fo);
        bf16x8 v2 = *(const bf16x8*)(feat + (size_t)i2 * 64 + fo);
        bf16x8 v3 = *(const bf16x8*)(feat + (size_t)i3 * 64 + fo);
#pragma unroll
        for (int k = 0; k < 8; ++k)
            acc[k] += ((float)v0[k] + (float)v1[k]) + ((float)v2[k] + (float)v3[k]);
    }
    for (; t < deg; ++t) {
        int i = csr[base + t];
        bf16x8 v = *(const bf16x8*)(feat + (size_t)i * 64 + fo);
#pragma unroll
        for (int k = 0; k < 8; ++k) acc[k] += (float)v[k];
    }
}

// Layer-1 aggregation: write bf16 mean1[N,64].
__global__ __launch_bounds__(256) void agg1_kernel(
    const unsigned short* __restrict__ feat, const int* __restrict__ rpack,
    const int* __restrict__ csr, unsigned int* __restrict__ mean1u) {
    int wid = threadIdx.x >> 6, lane = threadIdx.x & 63;
    int slot = lane >> 3, fo = (lane & 7) * 8;
    int d = (blockIdx.x * 4 + wid) * 8 + slot;
    int dd = min(d, NN - 1);
    int rp = rpack[dd];
    int base = rp >> 8;
    int deg = rp & 255;
    float acc[8];
#pragma unroll
    for (int k = 0; k < 8; ++k) acc[k] = 0.f;
    gather_acc(feat, csr, base, deg, fo, acc);
    if (d < NN) {
        float r = 1.0f / fmaxf((float)deg, 1.0f);
        uint4 o;
        o.x = f2b(acc[0] * r) | ((unsigned)f2b(acc[1] * r) << 16);
        o.y = f2b(acc[2] * r) | ((unsigned)f2b(acc[3] * r) << 16);
        o.z = f2b(acc[4] * r) | ((unsigned)f2b(acc[5] * r) << 16);
        o.w = f2b(acc[6] * r) | ((unsigned)f2b(acc[7] * r) << 16);
        *(uint4*)(mean1u + (size_t)d * 32 + (lane & 7) * 4) = o;
    }
}

// Layer-2 aggregation fused with final epilogue:
// out = mean(p) + sf + bias2  (store fp32 or bf16 per flags[1]).
__global__ __launch_bounds__(256) void agg2_kernel(
    const unsigned short* __restrict__ p, const int* __restrict__ rpack,
    const int* __restrict__ csr, const unsigned int* __restrict__ sfu,
    const float* __restrict__ bias2, const int* __restrict__ flags,
    void* __restrict__ out) {
    int wid = threadIdx.x >> 6, lane = threadIdx.x & 63;
    int slot = lane >> 3, fo = (lane & 7) * 8;
    int d = (blockIdx.x * 4 + wid) * 8 + slot;
    int dd = min(d, NN - 1);
    int rp = rpack[dd];
    int base = rp >> 8;
    int deg = rp & 255;
    float acc[8];
#pragma unroll
    for (int k = 0; k < 8; ++k) acc[k] = 0.f;
    gather_acc(p, csr, base, deg, fo, acc);
    if (d < NN) {
        float r = 1.0f / fmaxf((float)deg, 1.0f);
        uint4 sv = *(const uint4*)(sfu + (size_t)d * 32 + (lane & 7) * 4);
        float4 bA = *(const float4*)(bias2 + fo);
        float4 bB = *(const float4*)(bias2 + fo + 4);
        float v0 = acc[0] * r + b2f_lo(sv.x) + bA.x;
        float v1 = acc[1] * r + b2f_hi(sv.x) + bA.y;
        float v2 = acc[2] * r + b2f_lo(sv.y) + bA.z;
        float v3 = acc[3] * r + b2f_hi(sv.y) + bA.w;
        float v4 = acc[4] * r + b2f_lo(sv.z) + bB.x;
        float v5 = acc[5] * r + b2f_hi(sv.z) + bB.y;
        float v6 = acc[6] * r + b2f_lo(sv.w) + bB.z;
        float v7 = acc[7] * r + b2f_hi(sv.w) + bB.w;
        if (flags[1]) {
            float* op = (float*)out + (size_t)d * 64 + fo;
            *(float4*)op = make_float4(v0, v1, v2, v3);
            *(float4*)(op + 4) = make_float4(v4, v5, v6, v7);
        } else {
            uint4 o;
            o.x = f2b(v0) | ((unsigned)f2b(v1) << 16);
            o.y = f2b(v2) | ((unsigned)f2b(v3) << 16);
            o.z = f2b(v4) | ((unsigned)f2b(v5) << 16);
            o.w = f2b(v6) | ((unsigned)f2b(v7) << 16);
            *(uint4*)((unsigned int*)out + (size_t)d * 32 + (lane & 7) * 4) = o;
        }
    }
}

// Fused GEMM v2: 512 thr / 8 waves / 256 rows per block (wave = 2 m-tiles).
// Phase 1: h = relu([mean1|xb]@W1t + b1), W1 in LDS, A prefetched to regs.
// h -> per-wave LDS tile (no barrier).
// Phase 2: p = h@W2n, sf = h@(W2r+Wl2), W2 ALSO in LDS, B-fragments
// prefetched 8-wide per k-step.
__global__ __launch_bounds__(512, 2) void gemmF_kernel(
    const unsigned short* __restrict__ mean1,
    const unsigned short* __restrict__ xb,
    const unsigned short* __restrict__ Wt1g, const float* __restrict__ bias1,
    const unsigned short* __restrict__ Wt2g,
    unsigned short* __restrict__ p, unsigned short* __restrict__ sf) {
    __shared__ unsigned short Wt1s[128 * 136];   // 34,816 B
    __shared__ unsigned short Wt2s[128 * 136];   // 34,816 B
    __shared__ unsigned short hs[MB * 136];      // 69,632 B  (total 139,264 B)
    int tid = threadIdx.x;
    int wid = tid >> 6, lane = tid & 63;
    int m = lane & 15, g = lane >> 4;
    int row0 = blockIdx.x * MB + wid * 32;

    // prefetch A fragments for both m-tiles (hidden behind weight staging)
    bf16x8 a_frag[2][4];
#pragma unroll
    for (int t = 0; t < 2; ++t) {
        int arow = min(row0 + t * 16 + m, NN - 1);
#pragma unroll
        for (int kt = 0; kt < 4; ++kt) {
            int k0 = kt * 32 + g * 8;
            a_frag[t][kt] = (k0 < 64)
                ? *(const bf16x8*)(mean1 + (size_t)arow * 64 + k0)
                : *(const bf16x8*)(xb + (size_t)arow * 64 + (k0 - 64));
        }
    }

    // stage BOTH weight matrices into LDS (8 x 16B per thread)
    for (int idx = tid; idx < 4096; idx += 512) {
        int c = (idx >> 4) & 127, ch = idx & 15;
        if (idx < 2048)
            *(bf16x8*)&Wt1s[c * 136 + ch * 8] = *(const bf16x8*)&Wt1g[c * 128 + ch * 8];
        else
            *(bf16x8*)&Wt2s[c * 136 + ch * 8] = *(const bf16x8*)&Wt2g[c * 128 + ch * 8];
    }
    __syncthreads();

    f32x4 acc[2][8];
#pragma unroll
    for (int t = 0; t < 2; ++t)
#pragma unroll
        for (int nt = 0; nt < 8; ++nt) acc[t][nt] = (f32x4){0.f, 0.f, 0.f, 0.f};

#pragma unroll
    for (int kt = 0; kt < 4; ++kt) {
        int k0 = kt * 32 + g * 8;
        bf16x8 b[8];
#pragma unroll
        for (int nt = 0; nt < 8; ++nt)
            b[nt] = *(const bf16x8*)(&Wt1s[(nt * 16 + m) * 136 + k0]);
#pragma unroll
        for (int nt = 0; nt < 8; ++nt) {
            acc[0][nt] = __builtin_amdgcn_mfma_f32_16x16x32_bf16(a_frag[0][kt], b[nt], acc[0][nt], 0, 0, 0);
            acc[1][nt] = __builtin_amdgcn_mfma_f32_16x16x32_bf16(a_frag[1][kt], b[nt], acc[1][nt], 0, 0, 0);
        }
    }

    // phase-1 epilogue: relu+bias -> hs (wave's own 32-row slice)
#pragma unroll
    for (int t = 0; t < 2; ++t)
#pragma unroll
        for (int nt = 0; nt < 8; ++nt) {
            int col = nt * 16 + m;
            float bias = bias1[col];
#pragma unroll
            for (int r = 0; r < 4; ++r) {
                float v = fmaxf(acc[t][nt][r] + bias, 0.0f);
                hs[(wid * 32 + t * 16 + g * 4 + r) * 136 + col] = f2b(v);
            }
        }
    // no __syncthreads: each wave reads only rows it wrote itself.

    bf16x8 a2[2][4];
#pragma unroll
    for (int t = 0; t < 2; ++t)
#pragma unroll
        for (int kt = 0; kt < 4; ++kt)
            a2[t][kt] = *(const bf16x8*)(&hs[(wid * 32 + t * 16 + m) * 136 + kt * 32 + g * 8]);

#pragma unroll
    for (int t = 0; t < 2; ++t)
#pragma unroll
        for (int nt = 0; nt < 8; ++nt) acc[t][nt] = (f32x4){0.f, 0.f, 0.f, 0.f};

#pragma unroll
    for (int kt = 0; kt < 4; ++kt) {
        int k0 = kt * 32 + g * 8;
        bf16x8 b[8];
#pragma unroll
        for (int nt = 0; nt < 8; ++nt)
            b[nt] = *(const bf16x8*)(&Wt2s[(nt * 16 + m) * 136 + k0]);
#pragma unroll
        for (int nt = 0; nt < 8; ++nt) {
            acc[0][nt] = __builtin_amdgcn_mfma_f32_16x16x32_bf16(a2[0][kt], b[nt], acc[0][nt], 0, 0, 0);
            acc[1][nt] = __builtin_amdgcn_mfma_f32_16x16x32_bf16(a2[1][kt], b[nt], acc[1][nt], 0, 0, 0);
        }
    }

#pragma unroll
    for (int t = 0; t < 2; ++t)
#pragma unroll
        for (int nt = 0; nt < 8; ++nt) {
            int col = nt * 16 + m;
#pragma unroll
            for (int r = 0; r < 4; ++r) {
                int row2 = row0 + t * 16 + g * 4 + r;
                if (row2 < NN) {
                    float v = acc[t][nt][r];
                    if (col < 64) p[(size_t)row2 * 64 + col] = f2b(v);
                    else          sf[(size_t)row2 * 64 + (col - 64)] = f2b(v);
                }
            }
        }
}

extern "C" void kernel_launch(void* const* d_in, const int* in_sizes, int n_in,
                              void* d_out, int out_size, void* d_ws, size_t ws_size,
                              hipStream_t stream) {
    const void* x   = d_in[0];
    const int*  ei  = (const int*)d_in[1];
    const void* W1n = d_in[2];
    const void* b1n = d_in[3];
    const void* W1r = d_in[4];
    const void* Wl1 = d_in[5];
    const void* bl1 = d_in[6];
    const void* W2n = d_in[7];
    const void* b2n = d_in[8];
    const void* W2r = d_in[9];
    const void* Wl2 = d_in[10];
    const void* bl2 = d_in[11];

    char* ws = (char*)d_ws;
    // total ~55 MB; p aliases xb (block-local producer/consumer in gemmF)
    int*            flags = (int*)(ws + 0);                    //      64 B
    int*            cntP  = (int*)(ws + 1024);                 //  25,024 B (padded x16)
    float*          bias1 = (float*)(ws + 26112);              //     512 B
    float*          bias2 = (float*)(ws + 26624);              //     256 B
    unsigned short* Wt1g  = (unsigned short*)(ws + 26880);     //  32,768 B
    unsigned short* Wt2g  = (unsigned short*)(ws + 59648);     //  32,768 B
    int*            rpack = (int*)(ws + 92416);                // 400,000 B
    int*            csr   = (int*)(ws + 492544);               // 8,007,680 B (NSB*CAP2)
    unsigned short* xb    = (unsigned short*)(ws + 8500224);   // 12,800,000 B
    unsigned short* p     = xb;                                // (row-local alias)
    unsigned short* mean1 = (unsigned short*)(ws + 21300224);  // 12,800,000 B
    unsigned short* sf    = (unsigned short*)(ws + 34100224);  // 12,800,000 B
    int*            ebuf  = (int*)(ws + 46900224);             // 8,007,680 B

    (void)in_sizes; (void)n_in; (void)out_size; (void)ws_size;

    // zero super-bucket cursors (25KB memset node)
    hipMemsetAsync(cntP, 0, NSB * 16 * sizeof(int), stream);
    // fused front: bscatter + weight build + x canonicalization (flags inline)
    front_kernel<<<BSB + W1B + W2B + XBLK, 512, 0, stream>>>(
        x, ei, W1n, W1r, Wl1, b1n, bl1, W2n, W2r, Wl2, b2n, bl2,
        Wt1g, Wt2g, bias1, bias2, (unsigned int*)xb, flags, cntP, ebuf);
    // super-bucket CSR build (once, shared by both layers)
    csr_build_kernel<<<NSB, 512, 0, stream>>>(ebuf, cntP, rpack, csr);
    // layer 1 aggregation (32 dsts per block: 4 waves x 8 slots)
    agg1_kernel<<<(NN + 31) / 32, 256, 0, stream>>>(xb, rpack, csr, (unsigned int*)mean1);
    // fused GEMM v2 (256 rows/block, both weights in LDS)
    gemmF_kernel<<<(NN + MB - 1) / MB, 512, 0, stream>>>(mean1, xb, Wt1g, bias1, Wt2g, p, sf);
    // layer 2 aggregation + epilogue
    agg2_kernel<<<(NN + 31) / 32, 256, 0, stream>>>(p, rpack, csr, (const unsigned int*)sf,
                                                    bias2, flags, d_out);
}